// Round 2
// baseline (563.940 us; speedup 1.0000x reference)
//
#include <hip/hip_runtime.h>

#define BATCH 4
#define CH    512
#define NPIX  4096
#define LOG2E 1.4426950408889634f

typedef float v4f __attribute__((ext_vector_type(4)));
typedef short v8s __attribute__((ext_vector_type(8)));
typedef unsigned short u16;

__device__ __forceinline__ float b2f(u16 v){
    union { unsigned u; float f; } x; x.u = ((unsigned)v) << 16; return x.f;
}
__device__ __forceinline__ u16 f2b(float f){
    union { float f; unsigned u; } x; x.f = f;
    unsigned r = x.u + 0x7fffu + ((x.u >> 16) & 1u);   // RNE
    return (u16)(r >> 16);
}
__device__ __forceinline__ v4f mfma16(v8s a, v8s b, v4f c){
    return __builtin_amdgcn_mfma_f32_16x16x32_bf16(a, b, c, 0, 0, 0);
}

// ---------------------------------------------------------------------------
// dtype detector: fp32 N(0,1) words have bits[30:23] in ~[96,134];
// bf16-pair words land in [208,255] U [0,3]. Vote over 1024 words of x.
// ---------------------------------------------------------------------------
__global__ void detect_kernel(const unsigned* __restrict__ x, int* __restrict__ flag){
    __shared__ int cnt;
    if (threadIdx.x == 0) cnt = 0;
    __syncthreads();
    int c = 0;
    for (int i = threadIdx.x; i < 1024; i += 64){
        unsigned e = (x[i] >> 23) & 0xFFu;
        if (e >= 64u && e < 192u) c++;
    }
    atomicAdd(&cnt, c);
    __syncthreads();
    if (threadIdx.x == 0) flag[0] = (cnt > 512) ? 1 : 0;
}

// load 8 consecutive elements of a weight row as bf16 fragment
__device__ __forceinline__ v8s load_w8(const void* W, size_t idx, int isf32){
    if (isf32){
        const float* p = (const float*)W + idx;
        float4 f0 = *(const float4*)p;
        float4 f1 = *(const float4*)(p + 4);
        v8s r;
        r[0] = (short)f2b(f0.x); r[1] = (short)f2b(f0.y);
        r[2] = (short)f2b(f0.z); r[3] = (short)f2b(f0.w);
        r[4] = (short)f2b(f1.x); r[5] = (short)f2b(f1.y);
        r[6] = (short)f2b(f1.z); r[7] = (short)f2b(f1.w);
        return r;
    }
    return *(const v8s*)((const u16*)W + idx);
}
__device__ __forceinline__ float load_s(const void* p, size_t idx, int isf32){
    return isf32 ? ((const float*)p)[idx] : b2f(((const u16*)p)[idx]);
}

// ---------------------------------------------------------------------------
// Projection: Qt[b][n][64] = log2e*(wq x + bq)^T ; Kt[b][n][64] = (wk x + bk)^T
//             V [b][c][n]  = wv x + bv   (natural layout for PV A-operand)
// Grid: (N/64 n-tiles, 10 o-tiles, B). 256 thr = 4 waves.
// ---------------------------------------------------------------------------
__global__ __launch_bounds__(256) void proj_kernel(
    const void* __restrict__ x,
    const void* __restrict__ wq, const void* __restrict__ bq,
    const void* __restrict__ wk, const void* __restrict__ bk,
    const void* __restrict__ wv, const void* __restrict__ bv,
    u16* __restrict__ Qt, u16* __restrict__ Kt, u16* __restrict__ Vm,
    const int* __restrict__ flag)
{
    const int isf32 = flag[0];
    const int ntile = blockIdx.x;
    const int ot    = blockIdx.y;      // 0=Q, 1=K, 2..9 = V c-slabs
    const int b     = blockIdx.z;
    const int n0    = ntile * 64;
    const int t     = threadIdx.x;
    const int lane  = t & 63;
    const int w     = t >> 6;
    const int q     = lane >> 4;
    const int col   = lane & 15;

    __shared__ __align__(16) u16 xT[64 * 40];   // [n][c] stride 40
    __shared__ __align__(16) u16 vt[64 * 72];   // [c][n] stride 72

    const void* W; const void* bias; int orow;
    if (ot == 0)      { W = wq; bias = bq; orow = 0; }
    else if (ot == 1) { W = wk; bias = bk; orow = 0; }
    else              { W = wv; bias = bv; orow = (ot - 2) * 64; }

    const size_t xoff = (size_t)b * CH * NPIX;

    v4f acc[4];
    #pragma unroll
    for (int i = 0; i < 4; i++) acc[i] = (v4f){0.f, 0.f, 0.f, 0.f};

    const int cc = t & 31;           // c within 32-chunk
    const int g8 = (t >> 5) * 8;     // n col-group

    for (int c0 = 0; c0 < CH; c0 += 32){
        const size_t src = xoff + (size_t)(c0 + cc) * NPIX + n0 + g8;
        u16 vals[8];
        if (isf32){
            const float* xf = (const float*)x + src;
            float4 a0 = *(const float4*)xf;
            float4 a1 = *(const float4*)(xf + 4);
            vals[0] = f2b(a0.x); vals[1] = f2b(a0.y); vals[2] = f2b(a0.z); vals[3] = f2b(a0.w);
            vals[4] = f2b(a1.x); vals[5] = f2b(a1.y); vals[6] = f2b(a1.z); vals[7] = f2b(a1.w);
        } else {
            union { uint4 v; u16 s[8]; } ld;
            ld.v = *(const uint4*)((const u16*)x + src);
            #pragma unroll
            for (int i = 0; i < 8; i++) vals[i] = ld.s[i];
        }
        #pragma unroll
        for (int i = 0; i < 8; i++) xT[(g8 + i) * 40 + cc] = vals[i];
        __syncthreads();

        v8s a = *(const v8s*)&xT[(16 * w + col) * 40 + q * 8];   // A[m=n][k=c]
        #pragma unroll
        for (int ct = 0; ct < 4; ct++){
            v8s bf = load_w8(W, (size_t)(orow + 16 * ct + col) * CH + c0 + q * 8, isf32);
            acc[ct] = mfma16(a, bf, acc[ct]);
        }
        __syncthreads();
    }

    float bval[4];
    #pragma unroll
    for (int ct = 0; ct < 4; ct++) bval[ct] = load_s(bias, orow + 16 * ct + col, isf32);

    if (ot < 2){
        u16* dst = (ot == 0 ? Qt : Kt) + ((size_t)b * NPIX + n0) * 64;
        const float sc = (ot == 0) ? LOG2E : 1.0f;   // fold log2(e) into Q
        #pragma unroll
        for (int ct = 0; ct < 4; ct++)
            #pragma unroll
            for (int r = 0; r < 4; r++){
                float v = (acc[ct][r] + bval[ct]) * sc;
                dst[(16 * w + 4 * q + r) * 64 + 16 * ct + col] = f2b(v);
            }
    } else {
        #pragma unroll
        for (int ct = 0; ct < 4; ct++)
            #pragma unroll
            for (int r = 0; r < 4; r++)
                vt[(16 * ct + col) * 72 + 16 * w + 4 * q + r] = f2b(acc[ct][r] + bval[ct]);
        __syncthreads();
        const int cr = t >> 2;
        const int gg = (t & 3) * 16;
        uint4 d0 = *(const uint4*)&vt[cr * 72 + gg];
        uint4 d1 = *(const uint4*)&vt[cr * 72 + gg + 8];
        u16* dst = Vm + ((size_t)b * CH + orow + cr) * NPIX + n0 + gg;
        *(uint4*)dst       = d0;
        *(uint4*)(dst + 8) = d1;
    }
}

// ---------------------------------------------------------------------------
// Flash attention: per block = one 64-query tile. Bc=128 keys/iter.
// 512 thr = 8 waves: wave (rt=w&3, g=w>>2) computes S rows 16rt.., col half g;
// PV: wave w owns c-slab 64w..64w+63. O in [c][n] orientation.
// ---------------------------------------------------------------------------
__global__ __launch_bounds__(512) void attn_kernel(
    const u16* __restrict__ Qt, const u16* __restrict__ Kt, const u16* __restrict__ Vm,
    const void* __restrict__ x, const void* __restrict__ gamma, void* __restrict__ out,
    const int* __restrict__ flag)
{
    const int isf32 = flag[0];
    const int bid   = blockIdx.x;
    const int xcd   = bid & 7;
    const int b     = xcd >> 1;
    const int ntile = ((bid >> 3) << 1) | (xcd & 1);
    const int n0    = ntile * 64;

    const int t    = threadIdx.x;
    const int lane = t & 63;
    const int w    = t >> 6;
    const int rt   = w & 3;
    const int g    = w >> 2;
    const int q    = lane >> 4;
    const int col  = lane & 15;

    __shared__ __align__(16) u16  Plds[64 * 136];    // [n][m], stride 136
    __shared__ __align__(16) float m_s[64];
    __shared__ __align__(16) float l_s[64];
    __shared__ __align__(16) float alpha_s[64];
    __shared__ __align__(16) float pmax[2][64];
    __shared__ __align__(16) float psum[2][64];

    const u16* Qb = Qt + (size_t)b * NPIX * 64;
    const u16* Kb = Kt + (size_t)b * NPIX * 64;
    const u16* Vb = Vm + (size_t)b * CH * NPIX;

    v8s qa0 = *(const v8s*)&Qb[(n0 + 16 * rt + col) * 64 + q * 8];
    v8s qa1 = *(const v8s*)&Qb[(n0 + 16 * rt + col) * 64 + 32 + q * 8];

    if (t < 64){ m_s[t] = -1e9f; l_s[t] = 0.f; }

    v4f oacc[4][4];   // [ct][nt]
    #pragma unroll
    for (int i = 0; i < 4; i++)
        #pragma unroll
        for (int j = 0; j < 4; j++) oacc[i][j] = (v4f){0.f, 0.f, 0.f, 0.f};

    const int rbase = 16 * rt + 4 * q;

    for (int m0 = 0; m0 < NPIX; m0 += 128){
        // ---- S = Q K^T ----
        v4f s[4];
        #pragma unroll
        for (int j = 0; j < 4; j++){
            int mr = m0 + 16 * (4 * g + j) + col;
            v8s k0 = *(const v8s*)&Kb[mr * 64 + q * 8];
            v8s k1 = *(const v8s*)&Kb[mr * 64 + 32 + q * 8];
            v4f sv = (v4f){0.f, 0.f, 0.f, 0.f};
            sv = mfma16(qa0, k0, sv);
            sv = mfma16(qa1, k1, sv);
            s[j] = sv;
        }
        // ---- partial row max ----
        float pm[4];
        #pragma unroll
        for (int r = 0; r < 4; r++)
            pm[r] = fmaxf(fmaxf(s[0][r], s[1][r]), fmaxf(s[2][r], s[3][r]));
        #pragma unroll
        for (int mk = 1; mk < 16; mk <<= 1)
            #pragma unroll
            for (int r = 0; r < 4; r++)
                pm[r] = fmaxf(pm[r], __shfl_xor(pm[r], mk));
        if (col < 4){
            float v = pm[0];
            if (col == 1) v = pm[1];
            if (col == 2) v = pm[2];
            if (col == 3) v = pm[3];
            pmax[g][rbase + col] = v;
        }
        __syncthreads();

        // ---- combine max, alpha; P = exp2(S - m_new); partial sums ----
        v4f mo = *(const v4f*)&m_s[rbase];
        v4f p0 = *(const v4f*)&pmax[0][rbase];
        v4f p1 = *(const v4f*)&pmax[1][rbase];
        float mn[4], al[4];
        #pragma unroll
        for (int r = 0; r < 4; r++){
            mn[r] = fmaxf(mo[r], fmaxf(p0[r], p1[r]));
            al[r] = exp2f(fminf(mo[r] - mn[r], 0.f));
        }
        float ps[4] = {0.f, 0.f, 0.f, 0.f};
        #pragma unroll
        for (int j = 0; j < 4; j++)
            #pragma unroll
            for (int r = 0; r < 4; r++){
                float p = exp2f(fminf(s[j][r] - mn[r], 0.f));
                ps[r] += p;
                Plds[(rbase + r) * 136 + 16 * (4 * g + j) + col] = f2b(p);
            }
        #pragma unroll
        for (int mk = 1; mk < 16; mk <<= 1)
            #pragma unroll
            for (int r = 0; r < 4; r++)
                ps[r] += __shfl_xor(ps[r], mk);
        if (col < 4){
            float v = ps[0];
            if (col == 1) v = ps[1];
            if (col == 2) v = ps[2];
            if (col == 3) v = ps[3];
            psum[g][rbase + col] = v;
            if (g == 0){
                float a2 = al[0];
                if (col == 1) a2 = al[1];
                if (col == 2) a2 = al[2];
                if (col == 3) a2 = al[3];
                alpha_s[rbase + col] = a2;
            }
        }
        __syncthreads();

        // ---- stats update ----
        if (g == 0 && col == 0){
            v4f lo = *(const v4f*)&l_s[rbase];
            v4f s0 = *(const v4f*)&psum[0][rbase];
            v4f s1 = *(const v4f*)&psum[1][rbase];
            v4f mn4, ln4;
            #pragma unroll
            for (int r = 0; r < 4; r++){
                mn4[r] = mn[r];
                ln4[r] = al[r] * lo[r] + s0[r] + s1[r];
            }
            *(v4f*)&m_s[rbase] = mn4;
            *(v4f*)&l_s[rbase] = ln4;
        }

        // ---- rescale O ----
        float av[4];
        #pragma unroll
        for (int nt = 0; nt < 4; nt++) av[nt] = alpha_s[16 * nt + col];
        #pragma unroll
        for (int ct = 0; ct < 4; ct++)
            #pragma unroll
            for (int nt = 0; nt < 4; nt++){
                oacc[ct][nt][0] *= av[nt];
                oacc[ct][nt][1] *= av[nt];
                oacc[ct][nt][2] *= av[nt];
                oacc[ct][nt][3] *= av[nt];
            }

        // ---- O[c][n] += V[c][m] * P[n][m] ----
        #pragma unroll
        for (int kk = 0; kk < 4; kk++){
            v8s va[4], pb[4];
            #pragma unroll
            for (int ct = 0; ct < 4; ct++)
                va[ct] = *(const v8s*)&Vb[(size_t)(64 * w + 16 * ct + col) * NPIX + m0 + 32 * kk + q * 8];
            #pragma unroll
            for (int nt = 0; nt < 4; nt++)
                pb[nt] = *(const v8s*)&Plds[(16 * nt + col) * 136 + 32 * kk + q * 8];
            #pragma unroll
            for (int ct = 0; ct < 4; ct++)
                #pragma unroll
                for (int nt = 0; nt < 4; nt++)
                    oacc[ct][nt] = mfma16(va[ct], pb[nt], oacc[ct][nt]);
        }
    }

    __syncthreads();
    float gam = load_s(gamma, 0, isf32);
    float linv[4];
    #pragma unroll
    for (int nt = 0; nt < 4; nt++){
        float lv = l_s[16 * nt + col];
        linv[nt] = (lv > 0.f) ? 1.0f / lv : 0.f;
    }

    const size_t boff = (size_t)b * CH * NPIX;
    #pragma unroll
    for (int ct = 0; ct < 4; ct++){
        #pragma unroll
        for (int r = 0; r < 4; r++){
            int c = 64 * w + 16 * ct + 4 * q + r;
            size_t base = boff + (size_t)c * NPIX + n0;
            #pragma unroll
            for (int nt = 0; nt < 4; nt++){
                int n = 16 * nt + col;
                float o = gam * (oacc[ct][nt][r] * linv[nt]);
                if (isf32){
                    float xv = ((const float*)x)[base + n];
                    ((float*)out)[base + n] = o + xv;
                } else {
                    float xv = b2f(((const u16*)x)[base + n]);
                    ((u16*)out)[base + n] = f2b(o + xv);
                }
            }
        }
    }
}

// ---------------------------------------------------------------------------
extern "C" void kernel_launch(void* const* d_in, const int* in_sizes, int n_in,
                              void* d_out, int out_size, void* d_ws, size_t ws_size,
                              hipStream_t stream)
{
    const void* x     = d_in[0];
    const void* wq    = d_in[1];
    const void* bq    = d_in[2];
    const void* wk    = d_in[3];
    const void* bk    = d_in[4];
    const void* wv    = d_in[5];
    const void* bv    = d_in[6];
    const void* gamma = d_in[7];

    u16* Qt = (u16*)d_ws;                              // [B][N][64]
    u16* Kt = Qt + (size_t)BATCH * NPIX * 64;          // [B][N][64]
    u16* Vm = Kt + (size_t)BATCH * NPIX * 64;          // [B][C][N]
    int* flag = (int*)(Vm + (size_t)BATCH * CH * NPIX);

    detect_kernel<<<1, 64, 0, stream>>>((const unsigned*)x, flag);
    proj_kernel<<<dim3(NPIX / 64, 10, BATCH), 256, 0, stream>>>(
        x, wq, bq, wk, bk, wv, bv, Qt, Kt, Vm, flag);
    attn_kernel<<<dim3(64 * BATCH), 512, 0, stream>>>(
        Qt, Kt, Vm, x, gamma, d_out, flag);
}

// Round 3
// 455.312 us; speedup vs baseline: 1.2386x; 1.2386x over previous
//
#include <hip/hip_runtime.h>

#define BATCH 4
#define CH    512
#define NPIX  4096
#define LOG2E 1.4426950408889634f

// wbf segment offsets (elements)
#define WQ_OFF 0
#define WK_OFF 32768
#define WV_OFF 65536
#define BQ_OFF 327680
#define BK_OFF 327744
#define BV_OFF 327808
#define WTOT   328320

typedef float v4f __attribute__((ext_vector_type(4)));
typedef short v8s __attribute__((ext_vector_type(8)));
typedef unsigned short u16;

__device__ __forceinline__ float b2f(u16 v){
    union { unsigned u; float f; } x; x.u = ((unsigned)v) << 16; return x.f;
}
__device__ __forceinline__ u16 f2b(float f){
    union { float f; unsigned u; } x; x.f = f;
    unsigned r = x.u + 0x7fffu + ((x.u >> 16) & 1u);   // RNE
    return (u16)(r >> 16);
}
__device__ __forceinline__ v4f mfma16(v8s a, v8s b, v4f c){
    return __builtin_amdgcn_mfma_f32_16x16x32_bf16(a, b, c, 0, 0, 0);
}
__device__ __forceinline__ float fast_exp2(float x){
#if __has_builtin(__builtin_amdgcn_exp2f)
    return __builtin_amdgcn_exp2f(x);
#else
    return exp2f(x);
#endif
}
__device__ __forceinline__ float load_s(const void* p, size_t idx, int isf32){
    return isf32 ? ((const float*)p)[idx] : b2f(((const u16*)p)[idx]);
}

// ---------------------------------------------------------------------------
// dtype detector: fp32 N(0,1) words have exp bits in ~[96,134]; bf16-pair
// words land outside [64,192). Vote over 1024 words of x.
// ---------------------------------------------------------------------------
__global__ void detect_kernel(const unsigned* __restrict__ x, int* __restrict__ flag){
    __shared__ int cnt;
    if (threadIdx.x == 0) cnt = 0;
    __syncthreads();
    int c = 0;
    for (int i = threadIdx.x; i < 1024; i += 64){
        unsigned e = (x[i] >> 23) & 0xFFu;
        if (e >= 64u && e < 192u) c++;
    }
    atomicAdd(&cnt, c);
    __syncthreads();
    if (threadIdx.x == 0) flag[0] = (cnt > 512) ? 1 : 0;
}

// ---------------------------------------------------------------------------
// prep: convert all weights/biases to bf16 once (proj then loads v8s directly)
// ---------------------------------------------------------------------------
__global__ __launch_bounds__(256) void prep_kernel(
    const void* __restrict__ wq, const void* __restrict__ bq,
    const void* __restrict__ wk, const void* __restrict__ bk,
    const void* __restrict__ wv, const void* __restrict__ bv,
    u16* __restrict__ wbf, const int* __restrict__ flag)
{
    const int isf32 = flag[0];
    int i = blockIdx.x * 256 + threadIdx.x;
    if (i >= WTOT) return;
    const void* src; int off;
    if (i < WK_OFF)      { src = wq; off = i; }
    else if (i < WV_OFF) { src = wk; off = i - WK_OFF; }
    else if (i < BQ_OFF) { src = wv; off = i - WV_OFF; }
    else if (i < BK_OFF) { src = bq; off = i - BQ_OFF; }
    else if (i < BV_OFF) { src = bk; off = i - BK_OFF; }
    else                 { src = bv; off = i - BV_OFF; }
    wbf[i] = f2b(load_s(src, off, isf32));
}

// ---------------------------------------------------------------------------
// Projection, barrier-free K-loop: wave w stages ONLY its own 16 n-rows into a
// private LDS region (wave-synchronous transpose; in-order DS pipe => no
// __syncthreads needed). Weights read as bf16 v8s from wbf.
// Grid (64 ntiles, 10 ot, 4 b), 256 thr = 4 waves.
// ---------------------------------------------------------------------------
__global__ __launch_bounds__(256) void proj_kernel(
    const void* __restrict__ x, const u16* __restrict__ wbf,
    u16* __restrict__ Qt, u16* __restrict__ Kt, u16* __restrict__ Vm,
    const int* __restrict__ flag)
{
    const int isf32 = flag[0];
    const int ntile = blockIdx.x, ot = blockIdx.y, b = blockIdx.z;
    const int n0 = ntile * 64;
    const int t = threadIdx.x, lane = t & 63, w = t >> 6, q = lane >> 4, col = lane & 15;

    __shared__ __align__(16) u16 xT[4 * 2 * 16 * 40];   // per-wave dbuf [16 rows][40 c]
    __shared__ __align__(16) u16 vt[64 * 72];           // V epilogue transpose

    const u16* Wp; const u16* bias; int orow;
    if (ot == 0)      { Wp = wbf + WQ_OFF; bias = wbf + BQ_OFF; orow = 0; }
    else if (ot == 1) { Wp = wbf + WK_OFF; bias = wbf + BK_OFF; orow = 0; }
    else              { Wp = wbf + WV_OFF; bias = wbf + BV_OFF; orow = (ot - 2) * 64; }

    const int cgrp = lane >> 1;          // 0..31: c within chunk
    const int nh   = lane & 1;           // n half (8 each)
    const size_t xrowbase = ((size_t)b * CH + cgrp) * NPIX + n0 + 16 * w + 8 * nh;
    u16* myT = &xT[w * (2 * 16 * 40)];

    v4f acc[4];
    #pragma unroll
    for (int i = 0; i < 4; i++) acc[i] = (v4f){0.f, 0.f, 0.f, 0.f};

    #pragma unroll
    for (int cb = 0; cb < 16; cb++){
        const int c0 = cb * 32;
        const int buf = cb & 1;
        u16 vals[8];
        if (isf32){
            const float* p = (const float*)x + xrowbase + (size_t)c0 * NPIX;
            float4 a0 = *(const float4*)p;
            float4 a1 = *(const float4*)(p + 4);
            vals[0] = f2b(a0.x); vals[1] = f2b(a0.y); vals[2] = f2b(a0.z); vals[3] = f2b(a0.w);
            vals[4] = f2b(a1.x); vals[5] = f2b(a1.y); vals[6] = f2b(a1.z); vals[7] = f2b(a1.w);
        } else {
            union { uint4 v; u16 s[8]; } ld;
            ld.v = *(const uint4*)((const u16*)x + xrowbase + (size_t)c0 * NPIX);
            #pragma unroll
            for (int i = 0; i < 8; i++) vals[i] = ld.s[i];
        }
        #pragma unroll
        for (int i = 0; i < 8; i++)
            myT[(buf * 16 + 8 * nh + i) * 40 + cgrp] = vals[i];

        v8s a = *(const v8s*)&myT[(buf * 16 + col) * 40 + q * 8];   // A[m=n][k=c]
        #pragma unroll
        for (int ct = 0; ct < 4; ct++){
            v8s bf = *(const v8s*)&Wp[(size_t)(orow + 16 * ct + col) * CH + c0 + q * 8];
            acc[ct] = mfma16(a, bf, acc[ct]);
        }
    }

    float bval[4];
    #pragma unroll
    for (int ct = 0; ct < 4; ct++) bval[ct] = b2f(bias[orow + 16 * ct + col]);

    if (ot < 2){
        u16* dst = (ot == 0 ? Qt : Kt) + ((size_t)b * NPIX + n0) * 64;
        const float sc = (ot == 0) ? LOG2E : 1.0f;   // fold log2(e) into Q
        #pragma unroll
        for (int ct = 0; ct < 4; ct++)
            #pragma unroll
            for (int r = 0; r < 4; r++){
                float v = (acc[ct][r] + bval[ct]) * sc;
                dst[(16 * w + 4 * q + r) * 64 + 16 * ct + col] = f2b(v);
            }
    } else {
        #pragma unroll
        for (int ct = 0; ct < 4; ct++)
            #pragma unroll
            for (int r = 0; r < 4; r++)
                vt[(16 * ct + col) * 72 + 16 * w + 4 * q + r] = f2b(acc[ct][r] + bval[ct]);
        __syncthreads();
        const int cr = t >> 2;
        const int gg = (t & 3) * 16;
        uint4 d0 = *(const uint4*)&vt[cr * 72 + gg];
        uint4 d1 = *(const uint4*)&vt[cr * 72 + gg + 8];
        u16* dst = Vm + ((size_t)b * CH + orow + cr) * NPIX + n0 + gg;
        *(uint4*)dst       = d0;
        *(uint4*)(dst + 8) = d1;
    }
}

// ---------------------------------------------------------------------------
// Flash attention, c-split x kv-split. Grid 1024 = (32 nt-hi) x (ch 2) x
// (kv 2) x (xcd swizzle: b + nt-lo). Block = 4 waves (256 thr).
// Wave w: owns q-rows 16w..16w+15 (S + in-register online-softmax stats) and
// c-slab ch*256 + 64w (PV). P double-buffered in LDS -> ONE barrier per iter.
// Writes unnormalized partial O (bf16) + m,l (fp32) for the combine pass.
// ---------------------------------------------------------------------------
__global__ __launch_bounds__(256) void attn_kernel(
    const u16* __restrict__ Qt, const u16* __restrict__ Kt, const u16* __restrict__ Vm,
    u16* __restrict__ part, float* __restrict__ ml)
{
    const int bid = blockIdx.x;
    const int xcd = bid & 7;                 // XCD-locality: one batch per XCD pair
    const int b   = xcd >> 1;
    const int r   = bid >> 3;
    const int kv  = r & 1;
    const int ch  = (r >> 1) & 1;
    const int ntile = ((r >> 2) << 1) | (xcd & 1);
    const int n0 = ntile * 64;

    const int t = threadIdx.x, lane = t & 63, w = t >> 6, q = lane >> 4, col = lane & 15;

    __shared__ __align__(16) u16  Plds[2][64 * 136];
    __shared__ __align__(16) float alpha_s[2][64];

    const u16* Qb = Qt + (size_t)b * NPIX * 64;
    const u16* Kb = Kt + (size_t)b * NPIX * 64;
    const u16* Vb = Vm + (size_t)b * CH * NPIX;

    v8s qa0 = *(const v8s*)&Qb[(n0 + 16 * w + col) * 64 + q * 8];
    v8s qa1 = *(const v8s*)&Qb[(n0 + 16 * w + col) * 64 + 32 + q * 8];

    float mreg[4] = {-1e30f, -1e30f, -1e30f, -1e30f};
    float lreg[4] = {0.f, 0.f, 0.f, 0.f};

    v4f oacc[4][4];   // [ct: c][nt: n]
    #pragma unroll
    for (int i = 0; i < 4; i++)
        #pragma unroll
        for (int j = 0; j < 4; j++) oacc[i][j] = (v4f){0.f, 0.f, 0.f, 0.f};

    const int cbase = ch * 256 + w * 64;
    const int rloc  = 16 * w + 4 * q;        // this lane's quad row base

    for (int it = 0; it < 16; it++){
        const int m0 = kv * 2048 + it * 128;
        const int buf = it & 1;

        // ---- S = Q K^T : full 128 cols in this wave (16 MFMA) ----
        v4f s[8];
        #pragma unroll
        for (int j = 0; j < 8; j++){
            int mr = m0 + 16 * j + col;
            v8s k0 = *(const v8s*)&Kb[mr * 64 + q * 8];
            v8s k1 = *(const v8s*)&Kb[mr * 64 + 32 + q * 8];
            v4f sv = (v4f){0.f, 0.f, 0.f, 0.f};
            sv = mfma16(qa0, k0, sv);
            sv = mfma16(qa1, k1, sv);
            s[j] = sv;
        }

        // ---- in-wave row max (cols live in lane&15 within quad) ----
        float pm[4];
        #pragma unroll
        for (int rr = 0; rr < 4; rr++){
            float v = s[0][rr];
            #pragma unroll
            for (int j = 1; j < 8; j++) v = fmaxf(v, s[j][rr]);
            pm[rr] = v;
        }
        #pragma unroll
        for (int mk = 1; mk < 16; mk <<= 1)
            #pragma unroll
            for (int rr = 0; rr < 4; rr++)
                pm[rr] = fmaxf(pm[rr], __shfl_xor(pm[rr], mk));

        float mn[4], al[4];
        #pragma unroll
        for (int rr = 0; rr < 4; rr++){
            mn[rr] = fmaxf(mreg[rr], pm[rr]);
            al[rr] = fast_exp2(mreg[rr] - mn[rr]);
        }

        // ---- P = exp2(S - mn); write to LDS; partial row sums ----
        float ps[4] = {0.f, 0.f, 0.f, 0.f};
        #pragma unroll
        for (int j = 0; j < 8; j++)
            #pragma unroll
            for (int rr = 0; rr < 4; rr++){
                float p = fast_exp2(s[j][rr] - mn[rr]);
                ps[rr] += p;
                Plds[buf][(rloc + rr) * 136 + 16 * j + col] = f2b(p);
            }
        #pragma unroll
        for (int mk = 1; mk < 16; mk <<= 1)
            #pragma unroll
            for (int rr = 0; rr < 4; rr++)
                ps[rr] += __shfl_xor(ps[rr], mk);
        #pragma unroll
        for (int rr = 0; rr < 4; rr++){
            lreg[rr] = al[rr] * lreg[rr] + ps[rr];
            mreg[rr] = mn[rr];
        }
        if (col == 0){
            #pragma unroll
            for (int rr = 0; rr < 4; rr++) alpha_s[buf][rloc + rr] = al[rr];
        }

        __syncthreads();   // P[buf], alpha[buf] visible; prev buf free for overwrite

        // ---- rescale O by alpha(n), then O[c][n] += V[c][m] P[n][m] ----
        float av[4];
        #pragma unroll
        for (int nt = 0; nt < 4; nt++) av[nt] = alpha_s[buf][16 * nt + col];
        #pragma unroll
        for (int ct = 0; ct < 4; ct++)
            #pragma unroll
            for (int nt = 0; nt < 4; nt++){
                oacc[ct][nt][0] *= av[nt];
                oacc[ct][nt][1] *= av[nt];
                oacc[ct][nt][2] *= av[nt];
                oacc[ct][nt][3] *= av[nt];
            }
        #pragma unroll
        for (int kk = 0; kk < 4; kk++){
            v8s va[4], pb[4];
            #pragma unroll
            for (int ct = 0; ct < 4; ct++)
                va[ct] = *(const v8s*)&Vb[(size_t)(cbase + 16 * ct + col) * NPIX + m0 + 32 * kk + q * 8];
            #pragma unroll
            for (int nt = 0; nt < 4; nt++)
                pb[nt] = *(const v8s*)&Plds[buf][(16 * nt + col) * 136 + 32 * kk + q * 8];
            #pragma unroll
            for (int ct = 0; ct < 4; ct++)
                #pragma unroll
                for (int nt = 0; nt < 4; nt++)
                    oacc[ct][nt] = mfma16(va[ct], pb[nt], oacc[ct][nt]);
        }
    }

    // ---- write partial stats + unnormalized O ----
    const size_t poff = (size_t)(kv * BATCH + b) * 64 + ntile;
    if (col == 0){
        float* mlp = ml + poff * 128;
        #pragma unroll
        for (int rr = 0; rr < 4; rr++){
            mlp[rloc + rr]      = mreg[rr];   // both ch blocks write identical values
            mlp[64 + rloc + rr] = lreg[rr];
        }
    }
    u16* pp = part + poff * (512 * 64);
    #pragma unroll
    for (int ct = 0; ct < 4; ct++)
        #pragma unroll
        for (int rr = 0; rr < 4; rr++){
            int c = cbase + 16 * ct + 4 * q + rr;
            #pragma unroll
            for (int nt = 0; nt < 4; nt++)
                pp[(size_t)c * 64 + 16 * nt + col] = f2b(oacc[ct][nt][rr]);
        }
}

// ---------------------------------------------------------------------------
// combine: merge 2 kv partials, normalize, apply gamma + residual, write out.
// Grid 512 = (tile 256) x (c-half 2). 256 thr.
// ---------------------------------------------------------------------------
__global__ __launch_bounds__(256) void combine_kernel(
    const u16* __restrict__ part, const float* __restrict__ ml,
    const void* __restrict__ x, const void* __restrict__ gamma,
    void* __restrict__ out, const int* __restrict__ flag)
{
    const int isf32 = flag[0];
    const int bid = blockIdx.x;
    const int tile = bid >> 1;
    const int chh  = bid & 1;
    const int b = tile >> 6, ntile = tile & 63;
    const int n0 = ntile * 64;
    const int t = threadIdx.x;

    __shared__ float f0[64], f1[64];
    if (t < 64){
        const float* ml0 = ml + ((size_t)(0 * BATCH + b) * 64 + ntile) * 128;
        const float* ml1 = ml + ((size_t)(1 * BATCH + b) * 64 + ntile) * 128;
        float m0v = ml0[t], l0v = ml0[64 + t];
        float m1v = ml1[t], l1v = ml1[64 + t];
        float mx = fmaxf(m0v, m1v);
        float w0 = fast_exp2(m0v - mx), w1 = fast_exp2(m1v - mx);
        float den = w0 * l0v + w1 * l1v;
        float sc = load_s(gamma, 0, isf32) / den;
        f0[t] = sc * w0;
        f1[t] = sc * w1;
    }
    __syncthreads();

    const u16* p0 = part + ((size_t)(0 * BATCH + b) * 64 + ntile) * 32768;
    const u16* p1 = part + ((size_t)(1 * BATCH + b) * 64 + ntile) * 32768;
    const int nq  = (t & 15) * 4;
    const int cr0 = chh * 256 + (t >> 4);

    #pragma unroll
    for (int pass = 0; pass < 16; pass++){
        int c = cr0 + pass * 16;
        union { uint2 u; u16 s[4]; } a0, a1;
        a0.u = *(const uint2*)&p0[(size_t)c * 64 + nq];
        a1.u = *(const uint2*)&p1[(size_t)c * 64 + nq];
        size_t gx = ((size_t)b * CH + c) * NPIX + n0 + nq;
        if (isf32){
            float4 xv = *(const float4*)((const float*)x + gx);
            float4 o;
            o.x = f0[nq + 0] * b2f(a0.s[0]) + f1[nq + 0] * b2f(a1.s[0]) + xv.x;
            o.y = f0[nq + 1] * b2f(a0.s[1]) + f1[nq + 1] * b2f(a1.s[1]) + xv.y;
            o.z = f0[nq + 2] * b2f(a0.s[2]) + f1[nq + 2] * b2f(a1.s[2]) + xv.z;
            o.w = f0[nq + 3] * b2f(a0.s[3]) + f1[nq + 3] * b2f(a1.s[3]) + xv.w;
            *(float4*)((float*)out + gx) = o;
        } else {
            const u16* xb = (const u16*)x + gx;
            union { uint2 u; u16 s[4]; } ov;
            #pragma unroll
            for (int e = 0; e < 4; e++){
                float v = f0[nq + e] * b2f(a0.s[e]) + f1[nq + e] * b2f(a1.s[e]) + b2f(xb[e]);
                ov.s[e] = f2b(v);
            }
            *(uint2*)((u16*)out + gx) = ov.u;
        }
    }
}

// ---------------------------------------------------------------------------
extern "C" void kernel_launch(void* const* d_in, const int* in_sizes, int n_in,
                              void* d_out, int out_size, void* d_ws, size_t ws_size,
                              hipStream_t stream)
{
    const void* x     = d_in[0];
    const void* wq    = d_in[1];
    const void* bq    = d_in[2];
    const void* wk    = d_in[3];
    const void* bk    = d_in[4];
    const void* wv    = d_in[5];
    const void* bv    = d_in[6];
    const void* gamma = d_in[7];

    u16* Qt   = (u16*)d_ws;                       // [B][N][64]        1,048,576
    u16* Kt   = Qt + (size_t)1048576;             // [B][N][64]        1,048,576
    u16* Vm   = Kt + (size_t)1048576;             // [B][C][N]         8,388,608
    u16* part = Vm + (size_t)8388608;             // [2][B][64][512][64] 16,777,216
    u16* wbf  = part + (size_t)16777216;          // WTOT
    float* ml = (float*)(wbf + WTOT);             // [2][B][64][128]   65,536 fl
    int* flag = (int*)(ml + 65536);

    detect_kernel<<<1, 64, 0, stream>>>((const unsigned*)x, flag);
    prep_kernel<<<(WTOT + 255) / 256, 256, 0, stream>>>(wq, bq, wk, bk, wv, bv, wbf, flag);
    proj_kernel<<<dim3(64, 10, BATCH), 256, 0, stream>>>(x, wbf, Qt, Kt, Vm, flag);
    attn_kernel<<<1024, 256, 0, stream>>>(Qt, Kt, Vm, part, ml);
    combine_kernel<<<512, 256, 0, stream>>>(part, ml, x, gamma, d_out, flag);
}